// Round 9
// baseline (68055.548 us; speedup 1.0000x reference)
//
#include <hip/hip_runtime.h>
#include <math.h>

#define NN 256
#define HH 64

typedef unsigned int uint32;
typedef _Float16 h2f __attribute__((ext_vector_type(2)));

__device__ __forceinline__ float sigm(float x) { return 1.0f / (1.0f + expf(-x)); }

// 2 f16 MACs, f32 accumulate
__device__ __forceinline__ float dot2(uint32 a, uint32 b, float c) {
#if __has_builtin(__builtin_amdgcn_fdot2)
    return __builtin_amdgcn_fdot2(__builtin_bit_cast(h2f, a),
                                  __builtin_bit_cast(h2f, b), c, false);
#else
    h2f x = __builtin_bit_cast(h2f, a), y = __builtin_bit_cast(h2f, b);
    return c + (float)x[0] * (float)y[0] + (float)x[1] * (float)y[1];
#endif
}

// wave-uniform lane read (SGPR broadcast)
__device__ __forceinline__ uint32 rdlane(uint32 v, int l) {
#if __has_builtin(__builtin_amdgcn_readlane)
    return (uint32)__builtin_amdgcn_readlane((int)v, l);
#else
    return (uint32)__shfl((int)v, l);
#endif
}

// ---------------- R construction (fp64 GEMM chain) — proven ----------------
__global__ void k_affine(const float* __restrict__ A, float* __restrict__ Pout,
                         const float* __restrict__ tev, int div)
{
    int i = blockIdx.x, j = threadIdx.x;
    double h = (double)tev[1] - (double)tev[0];
    double v = (i == j ? 1.0 : 0.0) + (h / (double)div) * (double)A[i * NN + j];
    Pout[i * NN + j] = (float)v;
}

__global__ void k_gemm(const float* __restrict__ A, const float* __restrict__ Pin,
                       float* __restrict__ Pout, const float* __restrict__ tev, int div)
{
    int i = blockIdx.x, j = threadIdx.x;
    double h = (double)tev[1] - (double)tev[0];
    const float* Ar = A + i * NN;
    double acc = 0.0;
    for (int k = 0; k < NN; ++k) acc += (double)Ar[k] * (double)Pin[k * NN + j];
    double v = (i == j ? 1.0 : 0.0) + (h / (double)div) * acc;
    Pout[i * NN + j] = (float)v;
}

// gq = [g0 | g1 | g2 | g3 | q | ce]  (ce = MU * rowsum(R - I), fp64) — proven
__global__ void k_prep_vec(const float* __restrict__ A, const float* __restrict__ B,
                           const float* __restrict__ cooling, const float* __restrict__ tev,
                           const float* __restrict__ R, float* __restrict__ gq)
{
    __shared__ float heat[NN];
    __shared__ float vin[NN];
    int t = threadIdx.x;
    double h = (double)tev[1] - (double)tev[0];
    heat[t] = (t < NN - 2) ? 500.0f * sigm(cooling[t]) : 0.0f;
    __syncthreads();
    float B0 = B[t * (NN - 1)];
    double bh = 0.0;
    for (int j = 0; j < NN - 2; ++j) bh += (double)B[t * (NN - 1) + 1 + j] * (double)heat[j];
    vin[t] = B0; __syncthreads();
    double v1 = 0.0; for (int k = 0; k < NN; ++k) v1 += (double)A[t * NN + k] * (double)vin[k];
    __syncthreads(); vin[t] = (float)v1; __syncthreads();
    double v2 = 0.0; for (int k = 0; k < NN; ++k) v2 += (double)A[t * NN + k] * (double)vin[k];
    __syncthreads(); vin[t] = (float)v2; __syncthreads();
    double v3 = 0.0; for (int k = 0; k < NN; ++k) v3 += (double)A[t * NN + k] * (double)vin[k];
    __syncthreads();
    vin[t] = (float)bh; __syncthreads();
    double u1 = 0.0; for (int k = 0; k < NN; ++k) u1 += (double)A[t * NN + k] * (double)vin[k];
    __syncthreads(); vin[t] = (float)u1; __syncthreads();
    double u2 = 0.0; for (int k = 0; k < NN; ++k) u2 += (double)A[t * NN + k] * (double)vin[k];
    __syncthreads(); vin[t] = (float)u2; __syncthreads();
    double u3 = 0.0; for (int k = 0; k < NN; ++k) u3 += (double)A[t * NN + k] * (double)vin[k];

    double srow = 0.0;
    for (int c = 0; c < NN; ++c) srow += (double)R[t * NN + c];
    srow -= 1.0;                               // rowsum(E)

    gq[t]        = (float)((h / 6.0) * (double)B0);
    gq[256 + t]  = (float)((h * h / 6.0) * v1);
    gq[512 + t]  = (float)((h * h * h / 12.0) * v2);
    gq[768 + t]  = (float)((h * h * h * h / 24.0) * v3);
    gq[1024 + t] = (float)(h * bh + (h * h / 2.0) * u1 + (h * h * h / 6.0) * u2
                           + (h * h * h * h / 24.0) * u3);
    gq[1280 + t] = (float)(23.359 * srow);
}

__device__ __forceinline__ float interp1(float x, const float* __restrict__ ts,
                                         const float* __restrict__ vs, int n)
{
    int lo = 0, hi = n;
    while (lo < hi) { int mid = (lo + hi) >> 1; if (ts[mid] <= x) lo = mid + 1; else hi = mid; }
    int i = lo; if (i < 1) i = 1; if (i > n - 1) i = n - 1;
    float xim = ts[i - 1], xi = ts[i];
    float fim = vs[i - 1], fi = vs[i];
    return fim + (x - xim) / (xi - xim) * (fi - fim);
}

// td[k][0..7] = {S0,S1,S2,S3, sinD,cosD,sinW,cosW} — proven
__global__ void k_time(const float* __restrict__ tev, const float* __restrict__ tts,
                       const float* __restrict__ tvals, float* __restrict__ td,
                       int T, int ntout)
{
    int k = blockIdx.x * blockDim.x + threadIdx.x;
    if (k >= T) return;
    float t0 = tev[0];
    float dtf = tev[1] - t0;
    float t = tev[k] - t0;
    const float cD = (float)(2.0 * M_PI / 86400.0);
    const float cW = (float)(2.0 * M_PI / 604800.0);
    float f0 = (float)sin((double)(t * cD));
    float f1 = (float)cos((double)(t * cD));
    float f2 = (float)sin((double)(t * cW));
    float f3 = (float)cos((double)(t * cW));
    float To1 = interp1(t + t0, tts, tvals, ntout);
    float To2 = interp1((t + 0.5f * dtf) + t0, tts, tvals, ntout);
    float To4 = interp1((t + dtf) + t0, tts, tvals, ntout);
    size_t o = (size_t)k * 8;
    td[o + 0] = To1 + 4.0f * To2 + To4;
    td[o + 1] = To1 + 2.0f * To2;
    td[o + 2] = To1 + To2;
    td[o + 3] = To1;
    td[o + 4] = f0; td[o + 5] = f1; td[o + 6] = f2; td[o + 7] = f3;
}

// Pack E = 64*(R - I) as f16 pairs for 1024-thread k_main.
// Thread t (r=t&255, qt=t>>8) owns x'-dwords qt*32+i (i=0..31):
// Epk[t*32+i] = pack{E[r][64qt+2i], E[r][64qt+2i+1]}
__global__ void k_packE(const float* __restrict__ R, uint32* __restrict__ Epk)
{
    int d = blockIdx.x * 256 + threadIdx.x;   // 0..32767
    int t = d >> 5, i = d & 31;
    int r = t & 255, qt = t >> 8;
    int c = qt * 64 + 2 * i;
    float e0 = 64.0f * (R[r * NN + c]     - (r == c     ? 1.0f : 0.0f));
    float e1 = 64.0f * (R[r * NN + c + 1] - (r == c + 1 ? 1.0f : 0.0f));
    union { _Float16 h[2]; uint32 u; } p;
    p.h[0] = (_Float16)e0; p.h[1] = (_Float16)e1;
    Epk[d] = p.u;
}

// Pack w1 state-cols / 1.41 as f16 pairs for 1024-thread layout.
// Thread t (jr=t>>4, c=t&15): w1pk[t*8+i] = pack{w1[jr][16c+2i], +1} / 1.41
__global__ void k_packW(const float* __restrict__ w1, uint32* __restrict__ w1pk)
{
    int d = blockIdx.x * 256 + threadIdx.x;   // 0..8191
    int t = d >> 3, i = d & 7;
    int jr = t >> 4, c = t & 15;
    int col = 16 * c + 2 * i;
    const float is = 1.0f / 1.41f;
    union { _Float16 h[2]; uint32 u; } p;
    p.h[0] = (_Float16)(w1[jr * 260 + col] * is);
    p.h[1] = (_Float16)(w1[jr * 260 + col + 1] * is);
    w1pk[d] = p.u;
}

// ---------------- Sequential integrator ----------------
// 1024 threads (16 waves, 4/SIMD). Thread (r, qt) owns quarter-row of E in
// 32 VGPRs. x' distribution via 1 LDS b32/lane + v_readlane SGPR broadcast
// (VALU pipe) instead of per-thread LDS streams: LDS traffic 160KB -> ~5KB/step.
__global__
__attribute__((amdgpu_flat_work_group_size(1024, 1024)))
__attribute__((amdgpu_waves_per_eu(4, 4)))
void k_main(
    const float* __restrict__ tdata, const uint32* Epk,
    const uint32* __restrict__ w1pk, const float* __restrict__ gq,
    const float* __restrict__ w1g, const float* __restrict__ b1g,
    const float* __restrict__ w2g, float* out, int T)
{
    __shared__ __align__(16) uint32 spk[132];     // x' f16 pairs (128 used)
    __shared__ __align__(16) float part[4][NN];
    __shared__ float hspre[HH];                   // policy pre-activation
    __shared__ float b1eff[2][HH];
    __shared__ float wf[6 * HH];                  // w1f0..3, b1, w2
    __shared__ float td[2][8];

    const int t = threadIdx.x;
    const int r = t & 255;        // row
    const int qt = t >> 8;        // quarter (wave-uniform)
    const int jr = t >> 4;        // policy row 0..63
    const int c  = t & 15;        // policy chunk (16 cols = 8 dwords)
    const int lane = t & 63;

    // E quarter-row -> 32 VGPRs
    uint32 Ereg[32];
    {
        const uint4* Eg = reinterpret_cast<const uint4*>(Epk) + (size_t)t * 8;
        #pragma unroll
        for (int i = 0; i < 8; ++i) {
            uint4 v = Eg[i];
            Ereg[4 * i + 0] = v.x; Ereg[4 * i + 1] = v.y;
            Ereg[4 * i + 2] = v.z; Ereg[4 * i + 3] = v.w;
        }
    }
    // policy chunk -> 8 VGPRs
    uint32 Wreg[8];
    {
        const uint4* Wg = reinterpret_cast<const uint4*>(w1pk) + (size_t)t * 2;
        uint4 v = Wg[0]; Wreg[0] = v.x; Wreg[1] = v.y; Wreg[2] = v.z; Wreg[3] = v.w;
        v = Wg[1];       Wreg[4] = v.x; Wreg[5] = v.y; Wreg[6] = v.z; Wreg[7] = v.w;
    }
    // per-row constants in registers (used by t<256 only)
    float g0r = gq[r], g1r = gq[256 + r], g2r = gq[512 + r], g3r = gq[768 + r];
    float qr = gq[1024 + r], cer = gq[1280 + r];
    float w2r = w2g[lane];

    if (t < HH) {
        wf[t]       = w1g[t * 260 + 256];
        wf[64 + t]  = w1g[t * 260 + 257];
        wf[128 + t] = w1g[t * 260 + 258];
        wf[192 + t] = w1g[t * 260 + 259];
        wf[256 + t] = b1g[t];
        wf[320 + t] = w2g[t];
    }
    _Float16* sph = reinterpret_cast<_Float16*>(spk);
    float xr = 26.0f;                              // state for row t (t<256)
    if (t < NN) sph[t] = (_Float16)(26.0f - 23.359f);
    if (t < 8) td[0][t] = tdata[t];
    __syncthreads();
    if (t < HH)
        b1eff[0][t] = wf[256 + t] + wf[t] * td[0][4] + wf[64 + t] * td[0][5]
                    + wf[128 + t] * td[0][6] + wf[192 + t] * td[0][7];
    __syncthreads();

    const uint4* sp4 = reinterpret_cast<const uint4*>(spk);

    for (int k = 0; k < T; ++k) {
        const int cur = k & 1, nxt = cur ^ 1;
        float tdp = 0.0f;
        if (t >= 1016 && k + 1 < T) tdp = tdata[(size_t)(k + 1) * 8 + (t - 1016)];

        // ---- Phase A ----
        // policy partial: hs = (w1/1.41).x' over 16 cols (2 b128 reads)
        float hs = 0.0f;
        {
            uint4 s0 = sp4[c * 2], s1 = sp4[c * 2 + 1];
            hs = dot2(Wreg[0], s0.x, hs); hs = dot2(Wreg[1], s0.y, hs);
            hs = dot2(Wreg[2], s0.z, hs); hs = dot2(Wreg[3], s0.w, hs);
            hs = dot2(Wreg[4], s1.x, hs); hs = dot2(Wreg[5], s1.y, hs);
            hs = dot2(Wreg[6], s1.z, hs); hs = dot2(Wreg[7], s1.w, hs);
        }
        hs += __shfl_xor(hs, 1); hs += __shfl_xor(hs, 2);
        hs += __shfl_xor(hs, 4); hs += __shfl_xor(hs, 8);
        if (c == 0) hspre[jr] = hs;

        // matvec quarter-row: 1 LDS b32/lane, then 32 readlane+dot2 (VALU only)
        uint32 xld = spk[qt * 32 + (lane & 31)];
        float ac0 = 0.f, ac1 = 0.f, ac2 = 0.f, ac3 = 0.f;
        #pragma unroll
        for (int i = 0; i < 8; ++i) {
            uint32 u0 = rdlane(xld, 4 * i + 0);
            uint32 u1 = rdlane(xld, 4 * i + 1);
            uint32 u2 = rdlane(xld, 4 * i + 2);
            uint32 u3 = rdlane(xld, 4 * i + 3);
            ac0 = dot2(Ereg[4 * i + 0], u0, ac0);
            ac1 = dot2(Ereg[4 * i + 1], u1, ac1);
            ac2 = dot2(Ereg[4 * i + 2], u2, ac2);
            ac3 = dot2(Ereg[4 * i + 3], u3, ac3);
        }
        part[qt][r] = (ac0 + ac1) + (ac2 + ac3);

        if (t < NN) out[(size_t)k * NN + t] = xr;
        if (t >= 1016) td[nxt][t - 1016] = tdp;
        asm volatile("s_waitcnt lgkmcnt(0)\ns_barrier" ::: "memory");

        // ---- Phase B (row-owner waves 0-3; redundant action reduce) ----
        if (t < NN) {
            float h = tanhf(hspre[lane] + b1eff[cur][lane]);
            float v = w2r * h;
            v += __shfl_xor(v, 1);  v += __shfl_xor(v, 2);  v += __shfl_xor(v, 4);
            v += __shfl_xor(v, 8);  v += __shfl_xor(v, 16); v += __shfl_xor(v, 32);
            float aS = sigm(v);
            float S0 = td[cur][0], S1 = td[cur][1], S2 = td[cur][2], S3 = td[cur][3];
            float y = ((part[0][t] + part[1][t]) + (part[2][t] + part[3][t])) * 0.015625f;
            float xn = xr + y + cer
                     + S0 * g0r + S1 * g1r + S2 * g2r + S3 * g3r - aS * qr;
            xr = xn;
            sph[t] = (_Float16)(xn - 23.359f);
        } else if (t < 320 && k + 1 < T) {
            int j = t - 256;
            b1eff[nxt][j] = wf[256 + j] + wf[j] * td[nxt][4] + wf[64 + j] * td[nxt][5]
                          + wf[128 + j] * td[nxt][6] + wf[192 + j] * td[nxt][7];
        }
        asm volatile("s_waitcnt lgkmcnt(0)\ns_barrier" ::: "memory");
    }
}

extern "C" void kernel_launch(void* const* d_in, const int* in_sizes, int n_in,
                              void* d_out, int out_size, void* d_ws, size_t ws_size,
                              hipStream_t stream)
{
    (void)n_in; (void)out_size; (void)ws_size;
    const float* tev     = (const float*)d_in[0];
    const float* A       = (const float*)d_in[1];
    const float* B       = (const float*)d_in[2];
    const float* cooling = (const float*)d_in[3];
    const float* w1      = (const float*)d_in[4];
    const float* b1      = (const float*)d_in[5];
    const float* w2      = (const float*)d_in[6];
    const float* tts     = (const float*)d_in[7];
    const float* tvals   = (const float*)d_in[8];
    const int T     = in_sizes[0];
    const int ntout = in_sizes[7];

    float* out = (float*)d_out;
    float* ws  = (float*)d_ws;
    float*  R    = ws;                          // 65536 floats
    float*  gq   = ws + 65536;                  // 1536 floats
    uint32* w1pk = (uint32*)(ws + 67072);       // 8192 dwords
    float*  td   = ws + 75264;                  // T*8 floats
    float* P1 = out;                            // GEMM ping-pong (rewritten by k_main)
    float* P2 = out + 65536;
    size_t outN = (size_t)T * NN;
    uint32* Epk = (uint32*)(out + outN - 32768);  // 128 KB tail, read before overwritten

    hipLaunchKernelGGL(k_affine, dim3(256), dim3(256), 0, stream, A, P1, tev, 4);
    hipLaunchKernelGGL(k_gemm,   dim3(256), dim3(256), 0, stream, A, P1, P2, tev, 3);
    hipLaunchKernelGGL(k_gemm,   dim3(256), dim3(256), 0, stream, A, P2, P1, tev, 2);
    hipLaunchKernelGGL(k_gemm,   dim3(256), dim3(256), 0, stream, A, P1, R,  tev, 1);
    hipLaunchKernelGGL(k_packE,  dim3(128), dim3(256), 0, stream, R, Epk);
    hipLaunchKernelGGL(k_packW,  dim3(32),  dim3(256), 0, stream, w1, w1pk);
    hipLaunchKernelGGL(k_prep_vec, dim3(1), dim3(256), 0, stream, A, B, cooling, tev, R, gq);
    hipLaunchKernelGGL(k_time, dim3((T + 255) / 256), dim3(256), 0, stream,
                       tev, tts, tvals, td, T, ntout);
    hipLaunchKernelGGL(k_main, dim3(1), dim3(1024), 0, stream,
                       td, Epk, w1pk, gq, w1, b1, w2, out, T);
}